// Round 1
// baseline (19300.914 us; speedup 1.0000x reference)
//
#include <hip/hip_runtime.h>
#include <hip/hip_bf16.h>

#define NSEG 128
#define C1 256   // 4H
#define KD1 128  // 2H
#define C2 64    // H
#define EPSV 1e-5f

__device__ __forceinline__ float bf2f(unsigned short u){
  return __uint_as_float(((unsigned int)u) << 16);
}
__device__ __forceinline__ unsigned short f2bf(float f){
  unsigned int x = __float_as_uint(f);
  x += 0x7fffu + ((x >> 16) & 1u);   // round-to-nearest-even
  return (unsigned short)(x >> 16);
}

// ---------------- sort (counting sort by segment) ----------------
__global__ void k_hist(const int* __restrict__ col, const int* __restrict__ batch,
                       int* __restrict__ segE, int* __restrict__ cnt, int E){
  __shared__ int h[NSEG];
  for (int i = threadIdx.x; i < NSEG; i += blockDim.x) h[i] = 0;
  __syncthreads();
  int stride = gridDim.x * blockDim.x;
  for (int e = blockIdx.x * blockDim.x + threadIdx.x; e < E; e += stride){
    int s = batch[col[e]];
    segE[e] = s;
    atomicAdd(&h[s], 1);
  }
  __syncthreads();
  for (int i = threadIdx.x; i < NSEG; i += blockDim.x)
    if (h[i]) atomicAdd(&cnt[i], h[i]);
}

__global__ void k_scan(const int* __restrict__ cnt, int* __restrict__ cursor,
                       float* __restrict__ cntf){
  if (threadIdx.x == 0){
    int acc = 0;
    for (int i = 0; i < NSEG; i++){ cursor[i] = acc; acc += cnt[i]; }
  }
  if (threadIdx.x < NSEG){
    int c = cnt[threadIdx.x];
    cntf[threadIdx.x] = (float)(c > 0 ? c : 1);
  }
}

__global__ void k_scatter(const int* __restrict__ segE, int* __restrict__ cursor,
                          int* __restrict__ perm, int* __restrict__ segS,
                          int E, int epb){
  __shared__ int h[NSEG];
  __shared__ int base[NSEG];
  int b0 = blockIdx.x * epb;
  int b1 = b0 + epb < E ? b0 + epb : E;
  for (int i = threadIdx.x; i < NSEG; i += blockDim.x) h[i] = 0;
  __syncthreads();
  for (int e = b0 + threadIdx.x; e < b1; e += blockDim.x) atomicAdd(&h[segE[e]], 1);
  __syncthreads();
  for (int i = threadIdx.x; i < NSEG; i += blockDim.x)
    base[i] = h[i] ? atomicAdd(&cursor[i], h[i]) : 0;
  __syncthreads();
  for (int i = threadIdx.x; i < NSEG; i += blockDim.x) h[i] = 0;
  __syncthreads();
  for (int e = b0 + threadIdx.x; e < b1; e += blockDim.x){
    int s = segE[e];
    int p = base[s] + atomicAdd(&h[s], 1);
    perm[p] = e; segS[p] = s;
  }
}

// ---------------- pass A: GEMM1 + stats1 (+ optional y1 store) ----------------
template<bool STORE_Y1>
__global__ void __launch_bounds__(256, 2)
k_passA(const float* __restrict__ emb, const int* __restrict__ ei, int E,
        const float* __restrict__ W1,
        const int* __restrict__ perm, const int* __restrict__ segS,
        float* __restrict__ sum1, float* __restrict__ sq1,
        unsigned short* __restrict__ y1ws)
{
  const int tid = threadIdx.x;
  float w1c[KD1];
  #pragma unroll
  for (int k = 0; k < KD1; k++) w1c[k] = W1[k * C1 + tid];

  __shared__ float f12[8][KD1];
  __shared__ int ls_col[8], ls_row[8], ls_seg[8], ls_val[8];

  const int tile0 = blockIdx.x * 128;
  float ps = 0.f, pq = 0.f; int cur = -1;

  for (int sb = 0; sb < 16; ++sb){
    const int bpos = tile0 + sb * 8;
    if (tid < 8){
      int pos = bpos + tid;
      int v = (pos < E);
      ls_val[tid] = v;
      int p = v ? perm[pos] : 0;
      ls_col[tid] = ei[p];
      ls_row[tid] = ei[(size_t)E + p];
      ls_seg[tid] = v ? segS[pos] : 0;
    }
    __syncthreads();
    {
      int e = tid >> 5, q = tid & 31;
      const float* src = (q < 16) ? (emb + (size_t)ls_col[e] * 64 + q * 4)
                                  : (emb + (size_t)ls_row[e] * 64 + (q - 16) * 4);
      float4 v = *(const float4*)src;
      *(float4*)&f12[e][q * 4] = v;
    }
    __syncthreads();
    #pragma unroll 1
    for (int e = 0; e < 8; e++){
      if (!ls_val[e]) break;
      const float4* f4 = (const float4*)(&f12[e][0]);
      float a0 = 0.f, a1 = 0.f, a2 = 0.f, a3 = 0.f;
      #pragma unroll
      for (int k = 0; k < 32; k++){
        float4 v = f4[k];
        a0 = fmaf(v.x, w1c[4 * k + 0], a0);
        a1 = fmaf(v.y, w1c[4 * k + 1], a1);
        a2 = fmaf(v.z, w1c[4 * k + 2], a2);
        a3 = fmaf(v.w, w1c[4 * k + 3], a3);
      }
      float y = (a0 + a1) + (a2 + a3);
      int s = ls_seg[e];
      if (s != cur){
        if (cur >= 0){
          atomicAdd(&sum1[cur * C1 + tid], ps);
          atomicAdd(&sq1[cur * C1 + tid], pq);
        }
        ps = 0.f; pq = 0.f; cur = s;
      }
      ps += y; pq += y * y;
      if (STORE_Y1) y1ws[(size_t)(bpos + e) * C1 + tid] = f2bf(y);
    }
    __syncthreads();
  }
  if (cur >= 0){
    atomicAdd(&sum1[cur * C1 + tid], ps);
    atomicAdd(&sq1[cur * C1 + tid], pq);
  }
}

// ---------------- finalize stats -> scale/shift ----------------
__global__ void k_fin(const float* __restrict__ sum, const float* __restrict__ sq,
                      const float* __restrict__ cntf,
                      float* __restrict__ sc, float* __restrict__ sh, int C){
  int i = blockIdx.x * blockDim.x + threadIdx.x;
  if (i >= NSEG * C) return;
  int s = i / C;
  float c = cntf[s];
  float m = sum[i] / c;
  float v = fmaxf(sq[i] / c - m * m, 0.f);
  float inv = rsqrtf(v + EPSV);
  sc[i] = inv;
  sh[i] = -m * inv;
}

// ---------------- pass B: norm1+ReLU + GEMM2 (+stats2 / +store y2 / +final out) ----------------
template<bool LOAD_Y1, bool STORE_Y2, bool FINAL>
__global__ void __launch_bounds__(256, 2)
k_passB(const float* __restrict__ emb, const int* __restrict__ ei, int E,
        const float* __restrict__ W1, const float* __restrict__ W2,
        const int* __restrict__ perm, const int* __restrict__ segS,
        const float* __restrict__ sc1, const float* __restrict__ sh1,
        float* __restrict__ sum2, float* __restrict__ sq2,
        const unsigned short* __restrict__ y1ws,
        unsigned short* __restrict__ y2ws,
        const float* __restrict__ sc2, const float* __restrict__ sh2,
        const float* __restrict__ W3, const float* __restrict__ b3,
        float* __restrict__ out)
{
  const int tid = threadIdx.x;
  const int c2 = tid & 63;
  const int ks = tid >> 6;

  float w2c[64];
  #pragma unroll
  for (int k = 0; k < 64; k++) w2c[k] = W2[(ks * 64 + k) * C2 + c2];

  float w1c[LOAD_Y1 ? 1 : KD1];
  if constexpr (!LOAD_Y1){
    #pragma unroll
    for (int k = 0; k < KD1; k++) w1c[k] = W1[k * C1 + tid];
  }

  __shared__ float h1[8][C1];
  __shared__ float red[8][4][64];
  __shared__ float f12s[8][KD1];
  __shared__ int ls_p[8], ls_col[8], ls_row[8], ls_seg[8], ls_val[8];

  const int tile0 = blockIdx.x * 128;
  float ps = 0.f, pq = 0.f; int cur = -1;
  float w3v = 0.f, b3v = 0.f;
  if (FINAL){ w3v = W3[c2]; b3v = b3[0]; }

  for (int sb = 0; sb < 16; ++sb){
    const int bpos = tile0 + sb * 8;
    if (tid < 8){
      int pos = bpos + tid;
      int v = (pos < E);
      ls_val[tid] = v;
      int p = v ? perm[pos] : 0;
      ls_p[tid] = p;
      ls_col[tid] = ei[p];
      ls_row[tid] = ei[(size_t)E + p];
      ls_seg[tid] = v ? segS[pos] : 0;
    }
    __syncthreads();

    if constexpr (LOAD_Y1){
      #pragma unroll 1
      for (int e = 0; e < 8; e++){
        float hv = 0.f;
        if (ls_val[e]){
          int s = ls_seg[e];
          float y = bf2f(y1ws[(size_t)(bpos + e) * C1 + tid]);
          hv = fmaxf(fmaf(y, sc1[s * C1 + tid], sh1[s * C1 + tid]), 0.f);
        }
        h1[e][tid] = hv;
      }
    } else {
      {
        int e = tid >> 5, q = tid & 31;
        const float* src = (q < 16) ? (emb + (size_t)ls_col[e] * 64 + q * 4)
                                    : (emb + (size_t)ls_row[e] * 64 + (q - 16) * 4);
        float4 v = *(const float4*)src;
        *(float4*)&f12s[e][q * 4] = v;
      }
      __syncthreads();
      #pragma unroll 1
      for (int e = 0; e < 8; e++){
        float hv = 0.f;
        if (ls_val[e]){
          const float4* f4 = (const float4*)(&f12s[e][0]);
          float a0 = 0.f, a1 = 0.f, a2 = 0.f, a3 = 0.f;
          #pragma unroll
          for (int k = 0; k < 32; k++){
            float4 v = f4[k];
            a0 = fmaf(v.x, w1c[4 * k + 0], a0);
            a1 = fmaf(v.y, w1c[4 * k + 1], a1);
            a2 = fmaf(v.z, w1c[4 * k + 2], a2);
            a3 = fmaf(v.w, w1c[4 * k + 3], a3);
          }
          float y = (a0 + a1) + (a2 + a3);
          int s = ls_seg[e];
          hv = fmaxf(fmaf(y, sc1[s * C1 + tid], sh1[s * C1 + tid]), 0.f);
        }
        h1[e][tid] = hv;
      }
    }
    __syncthreads();

    // GEMM2 partials: thread (c2, ks) covers k in [ks*64, ks*64+64)
    #pragma unroll 1
    for (int e = 0; e < 8; e++){
      const float4* hf4 = (const float4*)(&h1[e][ks * 64]);
      float a0 = 0.f, a1 = 0.f, a2 = 0.f, a3 = 0.f;
      #pragma unroll
      for (int k = 0; k < 16; k++){
        float4 v = hf4[k];
        a0 = fmaf(v.x, w2c[4 * k + 0], a0);
        a1 = fmaf(v.y, w2c[4 * k + 1], a1);
        a2 = fmaf(v.z, w2c[4 * k + 2], a2);
        a3 = fmaf(v.w, w2c[4 * k + 3], a3);
      }
      red[e][ks][c2] = (a0 + a1) + (a2 + a3);
    }
    __syncthreads();

    #pragma unroll
    for (int p2 = 0; p2 < 2; p2++){
      int e = p2 * 4 + (tid >> 6);
      float y2v = red[e][0][c2] + red[e][1][c2] + red[e][2][c2] + red[e][3][c2];
      int valid = ls_val[e];
      int s = ls_seg[e];
      if constexpr (!FINAL){
        if (valid){
          if (s != cur){
            if (cur >= 0){
              atomicAdd(&sum2[cur * C2 + c2], ps);
              atomicAdd(&sq2[cur * C2 + c2], pq);
            }
            ps = 0.f; pq = 0.f; cur = s;
          }
          ps += y2v; pq += y2v * y2v;
          if (STORE_Y2) y2ws[(size_t)(bpos + e) * C2 + c2] = f2bf(y2v);
        }
      } else {
        float hv = fmaxf(fmaf(y2v, sc2[s * C2 + c2], sh2[s * C2 + c2]), 0.f);
        float a = hv * w3v;
        #pragma unroll
        for (int off = 32; off; off >>= 1) a += __shfl_xor(a, off);
        if (((tid & 63) == 0) && valid) out[ls_p[e]] = a + b3v;
      }
    }
    __syncthreads();
  }
  if constexpr (!FINAL){
    if (cur >= 0){
      atomicAdd(&sum2[cur * C2 + c2], ps);
      atomicAdd(&sq2[cur * C2 + c2], pq);
    }
  }
}

// ---------------- pass C: norm2+ReLU + W3 dot ----------------
__global__ void k_passC(const unsigned short* __restrict__ y2ws,
                        const int* __restrict__ perm, const int* __restrict__ segS,
                        const float* __restrict__ sc2, const float* __restrict__ sh2,
                        const float* __restrict__ W3, const float* __restrict__ b3,
                        float* __restrict__ out, int E)
{
  const int lane = threadIdx.x & 63;
  const int wid = (blockIdx.x * blockDim.x + threadIdx.x) >> 6;
  const int nw = (gridDim.x * blockDim.x) >> 6;
  const float w3v = W3[lane];
  const float b3v = b3[0];
  for (int pos = wid; pos < E; pos += nw){
    int s = segS[pos];
    float v = bf2f(y2ws[(size_t)pos * C2 + lane]);
    float h = fmaxf(fmaf(v, sc2[s * C2 + lane], sh2[s * C2 + lane]), 0.f);
    float a = h * w3v;
    #pragma unroll
    for (int off = 32; off; off >>= 1) a += __shfl_xor(a, off);
    if (lane == 0) out[perm[pos]] = a + b3v;
  }
}

extern "C" void kernel_launch(void* const* d_in, const int* in_sizes, int n_in,
                              void* d_out, int out_size, void* d_ws, size_t ws_size,
                              hipStream_t stream)
{
  const float* emb   = (const float*)d_in[0];
  const int*   ei    = (const int*)d_in[1];
  const int*   batch = (const int*)d_in[2];
  const float* W1    = (const float*)d_in[3];
  const float* W2    = (const float*)d_in[5];
  const float* W3    = (const float*)d_in[7];
  const float* b3    = (const float*)d_in[8];
  float* out = (float*)d_out;
  const int E = in_sizes[1] / 2;

  char* ws = (char*)d_ws;
  size_t o = 0;
  auto al = [&](size_t b){ size_t r = o; o = (o + b + 255) & ~((size_t)255); return r; };
  size_t o_segE = al((size_t)E * 4);
  size_t o_perm = al((size_t)E * 4);
  size_t o_segS = al((size_t)E * 4);
  size_t o_cnt  = al(NSEG * 4);
  size_t o_cur  = al(NSEG * 4);
  size_t o_cntf = al(NSEG * 4);
  size_t o_sum1 = al((size_t)NSEG * C1 * 4);
  size_t o_sq1  = al((size_t)NSEG * C1 * 4);
  size_t o_sc1  = al((size_t)NSEG * C1 * 4);
  size_t o_sh1  = al((size_t)NSEG * C1 * 4);
  size_t o_sum2 = al((size_t)NSEG * C2 * 4);
  size_t o_sq2  = al((size_t)NSEG * C2 * 4);
  size_t o_sc2  = al((size_t)NSEG * C2 * 4);
  size_t o_sh2  = al((size_t)NSEG * C2 * 4);
  size_t base_end = o;
  size_t o_y2 = al((size_t)E * C2 * 2);
  size_t need2 = o;
  size_t o_y1 = al((size_t)E * C1 * 2);
  size_t need1 = o;
  const bool have2 = ws_size >= need2;
  const bool have1 = ws_size >= need1;

  int* segE = (int*)(ws + o_segE);
  int* perm = (int*)(ws + o_perm);
  int* segS = (int*)(ws + o_segS);
  int* cnt  = (int*)(ws + o_cnt);
  int* curp = (int*)(ws + o_cur);
  float* cntf = (float*)(ws + o_cntf);
  float* sum1 = (float*)(ws + o_sum1);
  float* sq1  = (float*)(ws + o_sq1);
  float* sc1  = (float*)(ws + o_sc1);
  float* sh1  = (float*)(ws + o_sh1);
  float* sum2 = (float*)(ws + o_sum2);
  float* sq2  = (float*)(ws + o_sq2);
  float* sc2  = (float*)(ws + o_sc2);
  float* sh2  = (float*)(ws + o_sh2);
  unsigned short* y2p = (unsigned short*)(ws + o_y2);
  unsigned short* y1p = (unsigned short*)(ws + o_y1);

  hipMemsetAsync(ws + o_cnt, 0, base_end - o_cnt, stream);

  k_hist<<<2048, 256, 0, stream>>>(ei, batch, segE, cnt, E);
  k_scan<<<1, 128, 0, stream>>>(cnt, curp, cntf);
  const int epb = 2048;
  k_scatter<<<(E + epb - 1) / epb, 256, 0, stream>>>(segE, curp, perm, segS, E, epb);

  const int nT = (E + 127) / 128;
  if (have1)
    k_passA<true><<<nT, 256, 0, stream>>>(emb, ei, E, W1, perm, segS, sum1, sq1, y1p);
  else
    k_passA<false><<<nT, 256, 0, stream>>>(emb, ei, E, W1, perm, segS, sum1, sq1, nullptr);

  k_fin<<<(NSEG * C1) / 256, 256, 0, stream>>>(sum1, sq1, cntf, sc1, sh1, C1);

  if (have1)
    k_passB<true, true, false><<<nT, 256, 0, stream>>>(emb, ei, E, W1, W2, perm, segS,
        sc1, sh1, sum2, sq2, y1p, y2p, sc2, sh2, W3, b3, out);
  else if (have2)
    k_passB<false, true, false><<<nT, 256, 0, stream>>>(emb, ei, E, W1, W2, perm, segS,
        sc1, sh1, sum2, sq2, nullptr, y2p, sc2, sh2, W3, b3, out);
  else
    k_passB<false, false, false><<<nT, 256, 0, stream>>>(emb, ei, E, W1, W2, perm, segS,
        sc1, sh1, sum2, sq2, nullptr, nullptr, sc2, sh2, W3, b3, out);

  k_fin<<<(NSEG * C2) / 256, 256, 0, stream>>>(sum2, sq2, cntf, sc2, sh2, C2);

  if (have2)
    k_passC<<<2048, 256, 0, stream>>>(y2p, perm, segS, sc2, sh2, W3, b3, out, E);
  else
    k_passB<false, false, true><<<nT, 256, 0, stream>>>(emb, ei, E, W1, W2, perm, segS,
        sc1, sh1, sum2, sq2, nullptr, nullptr, sc2, sh2, W3, b3, out);
}

// Round 2
// 1364.028 us; speedup vs baseline: 14.1499x; 14.1499x over previous
//
#include <hip/hip_runtime.h>
#include <hip/hip_bf16.h>

#define NSEG 128
#define H64 64
#define C1 256   // 4H
#define K1 128   // 2H
#define C2 64    // H
#define EPSV 1e-5f

typedef __attribute__((ext_vector_type(8))) short bf16x8;
typedef __attribute__((ext_vector_type(4))) float f32x4;
typedef __attribute__((ext_vector_type(4))) unsigned int u32x4;

__device__ __forceinline__ unsigned short f2bf(float f){
  unsigned int x = __float_as_uint(f);
  x += 0x7fffu + ((x >> 16) & 1u);   // RNE
  return (unsigned short)(x >> 16);
}
__device__ __forceinline__ float bf2f(unsigned short u){
  return __uint_as_float(((unsigned int)u) << 16);
}

// ---------------- prep: dtype conversion / weight transpose ----------------
__global__ void k_cvt_emb(const float* __restrict__ src, unsigned short* __restrict__ dst, int n4){
  int i = blockIdx.x * blockDim.x + threadIdx.x;
  if (i >= n4) return;
  float4 v = ((const float4*)src)[i];
  unsigned int a = (unsigned int)f2bf(v.x) | ((unsigned int)f2bf(v.y) << 16);
  unsigned int b = (unsigned int)f2bf(v.z) | ((unsigned int)f2bf(v.w) << 16);
  ((uint2*)dst)[i] = make_uint2(a, b);
}

__global__ void k_cvt_w(const float* __restrict__ W1, const float* __restrict__ W2,
                        unsigned short* __restrict__ W1T, unsigned short* __restrict__ W2T){
  int i = blockIdx.x * blockDim.x + threadIdx.x;
  if (i < C1 * K1){                       // W1T[c][k] = W1[k][c]
    int c = i >> 7, k = i & 127;
    W1T[i] = f2bf(W1[k * C1 + c]);
  } else {
    int j = i - C1 * K1;
    if (j < C2 * C1){                     // W2T[c][k] = W2[k][c]
      int c = j >> 8, k = j & 255;
      W2T[j] = f2bf(W2[k * C2 + c]);
    }
  }
}

// ---------------- counting sort by segment ----------------
__global__ void k_hist(const int* __restrict__ col, const int* __restrict__ batch,
                       int* __restrict__ segE, int* __restrict__ cnt, int E){
  __shared__ int h[NSEG];
  for (int i = threadIdx.x; i < NSEG; i += blockDim.x) h[i] = 0;
  __syncthreads();
  int stride = gridDim.x * blockDim.x;
  for (int e = blockIdx.x * blockDim.x + threadIdx.x; e < E; e += stride){
    int s = batch[col[e]];
    segE[e] = s;
    atomicAdd(&h[s], 1);
  }
  __syncthreads();
  for (int i = threadIdx.x; i < NSEG; i += blockDim.x)
    if (h[i]) atomicAdd(&cnt[i], h[i]);
}

__global__ void k_scan(const int* __restrict__ cnt, int* __restrict__ cursor,
                       float* __restrict__ cntf){
  if (threadIdx.x == 0){
    int acc = 0;
    for (int i = 0; i < NSEG; i++){ cursor[i] = acc; acc += cnt[i]; }
  }
  if (threadIdx.x < NSEG){
    int c = cnt[threadIdx.x];
    cntf[threadIdx.x] = (float)(c > 0 ? c : 1);
  }
}

__global__ void k_scatter(const int* __restrict__ segE, const int* __restrict__ ei,
                          int* __restrict__ cursor, int* __restrict__ perm,
                          int* __restrict__ segS, int* __restrict__ ecol, int* __restrict__ erow,
                          int E, int epb){
  __shared__ int h[NSEG];
  __shared__ int base[NSEG];
  int b0 = blockIdx.x * epb;
  int b1 = b0 + epb < E ? b0 + epb : E;
  for (int i = threadIdx.x; i < NSEG; i += blockDim.x) h[i] = 0;
  __syncthreads();
  for (int e = b0 + threadIdx.x; e < b1; e += blockDim.x) atomicAdd(&h[segE[e]], 1);
  __syncthreads();
  for (int i = threadIdx.x; i < NSEG; i += blockDim.x)
    base[i] = h[i] ? atomicAdd(&cursor[i], h[i]) : 0;
  __syncthreads();
  for (int i = threadIdx.x; i < NSEG; i += blockDim.x) h[i] = 0;
  __syncthreads();
  for (int e = b0 + threadIdx.x; e < b1; e += blockDim.x){
    int s = segE[e];
    int p = base[s] + atomicAdd(&h[s], 1);
    perm[p] = e; segS[p] = s;
    ecol[p] = ei[e]; erow[p] = ei[(size_t)E + e];
  }
}

// ---------------- shared MFMA pieces ----------------
__device__ __forceinline__ bf16x8 ldWT(const unsigned short* WT, int crow, int kbase,
                                       int lane, int ldk){
  // lane -> row (crow + lane&15), k = kbase + (lane>>4)*8 .. +7
  return *(const bf16x8*)(WT + (size_t)(crow + (lane & 15)) * ldk + kbase + (lane >> 4) * 8);
}

__device__ __forceinline__ void stage_f12(char* f12b, const int* s_col, const int* s_row,
                                          const unsigned short* ebf, int tid){
  #pragma unroll
  for (int rep = 0; rep < 4; rep++){
    int c = rep * 256 + tid;
    int e = c >> 4, q = c & 15;
    const unsigned short* g = (q < 8) ? (ebf + (size_t)s_col[e] * H64 + q * 8)
                                      : (ebf + (size_t)s_row[e] * H64 + (q - 8) * 8);
    u32x4 v = *(const u32x4*)g;
    int byte = (e * 256 + q * 16) ^ ((e & 7) << 4);   // XOR swizzle (256B rows)
    *(u32x4*)(f12b + byte) = v;
  }
}

__device__ __forceinline__ void gemm1(const char* f12b, const unsigned short* W1T,
                                      int cbase, int lane, f32x4 acc[4][4]){
  #pragma unroll
  for (int kk = 0; kk < 4; kk++){
    bf16x8 bfr[4];
    #pragma unroll
    for (int nf = 0; nf < 4; nf++) bfr[nf] = ldWT(W1T, cbase + nf * 16, kk * 32, lane, K1);
    #pragma unroll
    for (int mf = 0; mf < 4; mf++){
      int row = mf * 16 + (lane & 15);
      int byte = (row * 256 + kk * 64 + (lane >> 4) * 16) ^ ((row & 7) << 4);
      bf16x8 a = *(const bf16x8*)(f12b + byte);
      #pragma unroll
      for (int nf = 0; nf < 4; nf++)
        acc[mf][nf] = __builtin_amdgcn_mfma_f32_16x16x32_bf16(a, bfr[nf], acc[mf][nf], 0, 0, 0);
    }
  }
}

// ---------------- pass 1: GEMM1 + per-(seg,channel) stats ----------------
__global__ void __launch_bounds__(256)
k_stats1(const unsigned short* __restrict__ ebf, const unsigned short* __restrict__ W1T,
         const int* __restrict__ ecol, const int* __restrict__ erow, const int* __restrict__ segS,
         float* __restrict__ sum1, float* __restrict__ sq1, int NT)
{
  __shared__ __align__(16) char f12b[16384];
  __shared__ int s_col[64], s_row[64], s_seg[64];
  const int tid = threadIdx.x, lane = tid & 63, w = tid >> 6;
  const int cbase = w * 64;
  float psum[4] = {0.f,0.f,0.f,0.f}, psq[4] = {0.f,0.f,0.f,0.f};
  int cur = -1;

  auto flush1 = [&](int seg){
    if (seg >= 0){
      #pragma unroll
      for (int nf = 0; nf < 4; nf++){
        float sv = psum[nf]; sv += __shfl_xor(sv, 16); sv += __shfl_xor(sv, 32);
        float qv = psq[nf];  qv += __shfl_xor(qv, 16); qv += __shfl_xor(qv, 32);
        if (lane < 16){
          atomicAdd(&sum1[seg * C1 + cbase + nf * 16 + lane], sv);
          atomicAdd(&sq1 [seg * C1 + cbase + nf * 16 + lane], qv);
        }
        psum[nf] = 0.f; psq[nf] = 0.f;
      }
    }
  };

  const int tEnd = (blockIdx.x * 16 + 16 < NT) ? blockIdx.x * 16 + 16 : NT;
  for (int t = blockIdx.x * 16; t < tEnd; t++){
    const int p0 = t * 64;
    __syncthreads();
    if (tid < 64){
      s_col[tid] = ecol[p0 + tid];
      s_row[tid] = erow[p0 + tid];
      s_seg[tid] = segS[p0 + tid];
    }
    __syncthreads();
    stage_f12(f12b, s_col, s_row, ebf, tid);
    __syncthreads();

    f32x4 acc[4][4];
    #pragma unroll
    for (int mf = 0; mf < 4; mf++)
      #pragma unroll
      for (int nf = 0; nf < 4; nf++) acc[mf][nf] = (f32x4){0.f,0.f,0.f,0.f};
    gemm1(f12b, W1T, cbase, lane, acc);

    int sA = s_seg[0], sB = s_seg[63];
    if (sA == sB){
      if (sA != cur){ flush1(cur); cur = sA; }
      #pragma unroll
      for (int mf = 0; mf < 4; mf++)
        #pragma unroll
        for (int r = 0; r < 4; r++)
          #pragma unroll
          for (int nf = 0; nf < 4; nf++){
            float v = acc[mf][nf][r];
            psum[nf] += v; psq[nf] += v * v;
          }
    } else {                     // rare: tile spans segment boundary
      flush1(cur); cur = -1;
      for (int s = sA; s <= sB; s++){
        float ts[4] = {0.f,0.f,0.f,0.f}, tq[4] = {0.f,0.f,0.f,0.f};
        #pragma unroll
        for (int mf = 0; mf < 4; mf++)
          #pragma unroll
          for (int r = 0; r < 4; r++){
            int e = mf * 16 + (lane >> 4) * 4 + r;
            bool m = (s_seg[e] == s);
            #pragma unroll
            for (int nf = 0; nf < 4; nf++){
              float v = m ? acc[mf][nf][r] : 0.f;
              ts[nf] += v; tq[nf] += v * v;
            }
          }
        #pragma unroll
        for (int nf = 0; nf < 4; nf++){
          float sv = ts[nf]; sv += __shfl_xor(sv, 16); sv += __shfl_xor(sv, 32);
          float qv = tq[nf]; qv += __shfl_xor(qv, 16); qv += __shfl_xor(qv, 32);
          if (lane < 16){
            atomicAdd(&sum1[s * C1 + cbase + nf * 16 + lane], sv);
            atomicAdd(&sq1 [s * C1 + cbase + nf * 16 + lane], qv);
          }
        }
      }
    }
  }
  flush1(cur);
}

// ---------------- finalize stats -> scale/shift ----------------
__global__ void k_fin(const float* __restrict__ sum, const float* __restrict__ sq,
                      const float* __restrict__ cntf,
                      float* __restrict__ sc, float* __restrict__ sh, int C){
  int i = blockIdx.x * blockDim.x + threadIdx.x;
  if (i >= NSEG * C) return;
  int s = i / C;
  float c = cntf[s];
  float m = sum[i] / c;
  float v = fmaxf(sq[i] / c - m * m, 0.f);
  float inv = rsqrtf(v + EPSV);
  sc[i] = inv;
  sh[i] = -m * inv;
}

// ---------------- pass 2: GEMM1 + norm1 + GEMM2 (+stats2/store y2 | final out) ----------------
// MODE 0: stats2 + store y2 ; MODE 1: stats2 only ; MODE 2: final output (needs sc2/sh2)
template<int MODE>
__global__ void __launch_bounds__(256)
k_mid(const unsigned short* __restrict__ ebf, const unsigned short* __restrict__ W1T,
      const unsigned short* __restrict__ W2T,
      const int* __restrict__ ecol, const int* __restrict__ erow,
      const int* __restrict__ segS, const int* __restrict__ perm,
      const float* __restrict__ sc1, const float* __restrict__ sh1,
      float* __restrict__ sum2, float* __restrict__ sq2,
      unsigned short* __restrict__ y2,
      const float* __restrict__ sc2, const float* __restrict__ sh2,
      const float* __restrict__ W3, const float* __restrict__ b3,
      float* __restrict__ out, int NT)
{
  __shared__ __align__(16) char f12b[16384];
  __shared__ __align__(16) char h1b[32768];
  __shared__ int s_col[64], s_row[64], s_seg[64];
  __shared__ float redL[4][64];
  const int tid = threadIdx.x, lane = tid & 63, w = tid >> 6;
  const int cbase = w * 64;          // GEMM1 output channels of this wave
  const int c2b = w * 16;            // GEMM2 output channels of this wave
  float psum = 0.f, psq = 0.f; int cur = -1;
  float w3l = 0.f, b3v = 0.f;
  if (MODE == 2){ w3l = W3[c2b + (lane & 15)]; b3v = b3[0]; }

  auto flush2 = [&](int seg){
    if (seg >= 0){
      float sv = psum; sv += __shfl_xor(sv, 16); sv += __shfl_xor(sv, 32);
      float qv = psq;  qv += __shfl_xor(qv, 16); qv += __shfl_xor(qv, 32);
      if (lane < 16){
        atomicAdd(&sum2[seg * C2 + c2b + lane], sv);
        atomicAdd(&sq2 [seg * C2 + c2b + lane], qv);
      }
      psum = 0.f; psq = 0.f;
    }
  };

  const int tEnd = (blockIdx.x * 16 + 16 < NT) ? blockIdx.x * 16 + 16 : NT;
  for (int t = blockIdx.x * 16; t < tEnd; t++){
    const int p0 = t * 64;
    __syncthreads();
    if (tid < 64){
      s_col[tid] = ecol[p0 + tid];
      s_row[tid] = erow[p0 + tid];
      s_seg[tid] = segS[p0 + tid];
    }
    __syncthreads();
    stage_f12(f12b, s_col, s_row, ebf, tid);
    __syncthreads();

    f32x4 acc1[4][4];
    #pragma unroll
    for (int mf = 0; mf < 4; mf++)
      #pragma unroll
      for (int nf = 0; nf < 4; nf++) acc1[mf][nf] = (f32x4){0.f,0.f,0.f,0.f};
    gemm1(f12b, W1T, cbase, lane, acc1);

    const int sA = s_seg[0], sB = s_seg[63];
    const bool uni = (sA == sB);

    // ---- norm1 + relu -> h1 (bf16, swizzled LDS) ----
    float scv[4], shv[4];
    if (uni){
      #pragma unroll
      for (int nf = 0; nf < 4; nf++){
        scv[nf] = sc1[sA * C1 + cbase + nf * 16 + (lane & 15)];
        shv[nf] = sh1[sA * C1 + cbase + nf * 16 + (lane & 15)];
      }
    }
    #pragma unroll
    for (int mf = 0; mf < 4; mf++)
      #pragma unroll
      for (int r = 0; r < 4; r++){
        int e = mf * 16 + (lane >> 4) * 4 + r;
        int svseg = uni ? sA : s_seg[e];
        #pragma unroll
        for (int nf = 0; nf < 4; nf++){
          float sc = uni ? scv[nf] : sc1[svseg * C1 + cbase + nf * 16 + (lane & 15)];
          float sh = uni ? shv[nf] : sh1[svseg * C1 + cbase + nf * 16 + (lane & 15)];
          float hv = fmaxf(fmaf(acc1[mf][nf][r], sc, sh), 0.f);
          int cch = cbase + nf * 16 + (lane & 15);
          int byte = (e * 512 + cch * 2) ^ ((e & 7) << 4);   // XOR swizzle (512B rows)
          *(short*)(h1b + byte) = (short)f2bf(hv);
        }
      }
    __syncthreads();

    // ---- GEMM2: [64 edges] x [K=256] x [16 ch per wave] ----
    f32x4 acc2[4];
    #pragma unroll
    for (int mf = 0; mf < 4; mf++) acc2[mf] = (f32x4){0.f,0.f,0.f,0.f};
    #pragma unroll
    for (int kk = 0; kk < 8; kk++){
      bf16x8 b = ldWT(W2T, c2b, kk * 32, lane, C1);
      #pragma unroll
      for (int mf = 0; mf < 4; mf++){
        int row = mf * 16 + (lane & 15);
        int byte = (row * 512 + kk * 64 + (lane >> 4) * 16) ^ ((row & 7) << 4);
        bf16x8 a = *(const bf16x8*)(h1b + byte);
        acc2[mf] = __builtin_amdgcn_mfma_f32_16x16x32_bf16(a, b, acc2[mf], 0, 0, 0);
      }
    }

    if (MODE < 2){
      // ---- stats2 ----
      if (uni){
        if (sA != cur){ flush2(cur); cur = sA; }
        #pragma unroll
        for (int mf = 0; mf < 4; mf++)
          #pragma unroll
          for (int r = 0; r < 4; r++){
            float v = acc2[mf][r];
            psum += v; psq += v * v;
          }
      } else {
        flush2(cur); cur = -1;
        for (int s = sA; s <= sB; s++){
          float ts = 0.f, tq = 0.f;
          #pragma unroll
          for (int mf = 0; mf < 4; mf++)
            #pragma unroll
            for (int r = 0; r < 4; r++){
              int e = mf * 16 + (lane >> 4) * 4 + r;
              float v = (s_seg[e] == s) ? acc2[mf][r] : 0.f;
              ts += v; tq += v * v;
            }
          float sv = ts; sv += __shfl_xor(sv, 16); sv += __shfl_xor(sv, 32);
          float qv = tq; qv += __shfl_xor(qv, 16); qv += __shfl_xor(qv, 32);
          if (lane < 16){
            atomicAdd(&sum2[s * C2 + c2b + lane], sv);
            atomicAdd(&sq2 [s * C2 + c2b + lane], qv);
          }
        }
      }
      if (MODE == 0){
        #pragma unroll
        for (int mf = 0; mf < 4; mf++)
          #pragma unroll
          for (int r = 0; r < 4; r++){
            int e = mf * 16 + (lane >> 4) * 4 + r;
            y2[(size_t)(p0 + e) * C2 + c2b + (lane & 15)] = f2bf(acc2[mf][r]);
          }
      }
    } else {
      // ---- MODE 2: norm2 + relu + W3 dot + output ----
      float scv2 = 0.f, shv2 = 0.f;
      if (uni){
        scv2 = sc2[sA * C2 + c2b + (lane & 15)];
        shv2 = sh2[sA * C2 + c2b + (lane & 15)];
      }
      #pragma unroll
      for (int mf = 0; mf < 4; mf++)
        #pragma unroll
        for (int r = 0; r < 4; r++){
          int e = mf * 16 + (lane >> 4) * 4 + r;
          int svseg = uni ? sA : s_seg[e];
          float sc = uni ? scv2 : sc2[svseg * C2 + c2b + (lane & 15)];
          float sh = uni ? shv2 : sh2[svseg * C2 + c2b + (lane & 15)];
          float pv = fmaxf(fmaf(acc2[mf][r], sc, sh), 0.f) * w3l;
          pv += __shfl_xor(pv, 1); pv += __shfl_xor(pv, 2);
          pv += __shfl_xor(pv, 4); pv += __shfl_xor(pv, 8);
          if ((lane & 15) == 0) redL[w][e] = pv;
        }
      __syncthreads();
      if (tid < 64){
        float o = redL[0][tid] + redL[1][tid] + redL[2][tid] + redL[3][tid] + b3v;
        out[perm[p0 + tid]] = o;
      }
    }
  }
  if (MODE < 2) flush2(cur);
}

// ---------------- pass 3: norm2 + relu + W3 dot (from stored y2) ----------------
__global__ void k_out(const unsigned short* __restrict__ y2, const int* __restrict__ segS,
                      const int* __restrict__ perm, const float* __restrict__ sc2,
                      const float* __restrict__ sh2, const float* __restrict__ W3,
                      const float* __restrict__ b3, float* __restrict__ out, int E)
{
  const int lane = threadIdx.x & 63;
  const int wid = (blockIdx.x * blockDim.x + threadIdx.x) >> 6;
  const int nw = (gridDim.x * blockDim.x) >> 6;
  const int es = lane >> 3;        // edge sub-index within wave (0..7)
  const int cp = (lane & 7) * 8;   // channel base (8 per lane)
  float w3r[8];
  #pragma unroll
  for (int j = 0; j < 8; j++) w3r[j] = W3[cp + j];
  const float b3v = b3[0];
  for (long base = (long)wid * 8; base < E; base += (long)nw * 8){
    int pos = (int)base + es;
    float a = 0.f;
    if (pos < E){
      bf16x8 v = *(const bf16x8*)(y2 + (size_t)pos * C2 + cp);
      int s = segS[pos];
      const float* scp = sc2 + s * C2 + cp;
      const float* shp = sh2 + s * C2 + cp;
      #pragma unroll
      for (int j = 0; j < 8; j++){
        float hv = fmaxf(fmaf(bf2f((unsigned short)v[j]), scp[j], shp[j]), 0.f);
        a = fmaf(hv, w3r[j], a);
      }
    }
    a += __shfl_xor(a, 1); a += __shfl_xor(a, 2); a += __shfl_xor(a, 4);
    if ((lane & 7) == 0 && pos < E) out[perm[pos]] = a + b3v;
  }
}

// ---------------- launch ----------------
extern "C" void kernel_launch(void* const* d_in, const int* in_sizes, int n_in,
                              void* d_out, int out_size, void* d_ws, size_t ws_size,
                              hipStream_t stream)
{
  const float* emb   = (const float*)d_in[0];
  const int*   ei    = (const int*)d_in[1];
  const int*   batch = (const int*)d_in[2];
  const float* W1    = (const float*)d_in[3];
  const float* W2    = (const float*)d_in[5];
  const float* W3    = (const float*)d_in[7];
  const float* b3    = (const float*)d_in[8];
  float* out = (float*)d_out;
  const int E = in_sizes[1] / 2;
  const int N = in_sizes[0] / H64;
  const int NT = E / 64;                 // E = 1.6M -> exact

  char* ws = (char*)d_ws;
  size_t o = 0;
  auto al = [&](size_t b){ size_t r = o; o = (o + b + 255) & ~((size_t)255); return r; };
  size_t o_ebf  = al((size_t)N * H64 * 2);
  size_t o_w1t  = al((size_t)C1 * K1 * 2);
  size_t o_w2t  = al((size_t)C2 * C1 * 2);
  size_t o_perm = al((size_t)E * 4);
  size_t o_segS = al((size_t)E * 4);
  size_t o_ecol = al((size_t)E * 4);
  size_t o_erow = al((size_t)E * 4);
  size_t o_cnt  = al(NSEG * 4);
  size_t o_cur  = al(NSEG * 4);
  size_t o_cntf = al(NSEG * 4);
  size_t o_sum1 = al((size_t)NSEG * C1 * 4);
  size_t o_sq1  = al((size_t)NSEG * C1 * 4);
  size_t o_sum2 = al((size_t)NSEG * C2 * 4);
  size_t o_sq2  = al((size_t)NSEG * C2 * 4);
  size_t o_sc1  = al((size_t)NSEG * C1 * 4);
  size_t o_sh1  = al((size_t)NSEG * C1 * 4);
  size_t o_sc2  = al((size_t)NSEG * C2 * 4);
  size_t o_sh2  = al((size_t)NSEG * C2 * 4);
  size_t o_segE = al((size_t)E * 4);
  size_t o_y2   = o_segE;                 // y2 aliases segE (segE dead after sort)
  size_t need_full = o_segE + (size_t)E * C2 * 2;
  const bool full = ws_size >= need_full;

  unsigned short* ebf = (unsigned short*)(ws + o_ebf);
  unsigned short* W1T = (unsigned short*)(ws + o_w1t);
  unsigned short* W2T = (unsigned short*)(ws + o_w2t);
  int* perm = (int*)(ws + o_perm);
  int* segS = (int*)(ws + o_segS);
  int* ecol = (int*)(ws + o_ecol);
  int* erow = (int*)(ws + o_erow);
  int* cnt  = (int*)(ws + o_cnt);
  int* curp = (int*)(ws + o_cur);
  float* cntf = (float*)(ws + o_cntf);
  float* sum1 = (float*)(ws + o_sum1);
  float* sq1  = (float*)(ws + o_sq1);
  float* sum2 = (float*)(ws + o_sum2);
  float* sq2  = (float*)(ws + o_sq2);
  float* sc1  = (float*)(ws + o_sc1);
  float* sh1  = (float*)(ws + o_sh1);
  float* sc2  = (float*)(ws + o_sc2);
  float* sh2  = (float*)(ws + o_sh2);
  int* segE = (int*)(ws + o_segE);
  unsigned short* y2 = (unsigned short*)(ws + o_y2);

  // zero cnt..sq2 (contiguous)
  hipMemsetAsync(ws + o_cnt, 0, o_sc1 - o_cnt, stream);

  k_cvt_emb<<<(N * H64 / 4 + 255) / 256, 256, 0, stream>>>(emb, ebf, N * H64 / 4);
  k_cvt_w<<<192, 256, 0, stream>>>(W1, W2, W1T, W2T);

  k_hist<<<2048, 256, 0, stream>>>(ei, batch, segE, cnt, E);
  k_scan<<<1, 128, 0, stream>>>(cnt, curp, cntf);
  const int epb = 2048;
  k_scatter<<<(E + epb - 1) / epb, 256, 0, stream>>>(segE, ei, curp, perm, segS, ecol, erow, E, epb);

  const int nB = (NT + 15) / 16;
  k_stats1<<<nB, 256, 0, stream>>>(ebf, W1T, ecol, erow, segS, sum1, sq1, NT);
  k_fin<<<(NSEG * C1) / 256, 256, 0, stream>>>(sum1, sq1, cntf, sc1, sh1, C1);

  if (full){
    k_mid<0><<<nB, 256, 0, stream>>>(ebf, W1T, W2T, ecol, erow, segS, perm,
        sc1, sh1, sum2, sq2, y2, sc2, sh2, W3, b3, out, NT);
    k_fin<<<(NSEG * C2) / 256, 256, 0, stream>>>(sum2, sq2, cntf, sc2, sh2, C2);
    k_out<<<1024, 256, 0, stream>>>(y2, segS, perm, sc2, sh2, W3, b3, out, E);
  } else {
    k_mid<1><<<nB, 256, 0, stream>>>(ebf, W1T, W2T, ecol, erow, segS, perm,
        sc1, sh1, sum2, sq2, nullptr, sc2, sh2, W3, b3, out, NT);
    k_fin<<<(NSEG * C2) / 256, 256, 0, stream>>>(sum2, sq2, cntf, sc2, sh2, C2);
    k_mid<2><<<nB, 256, 0, stream>>>(ebf, W1T, W2T, ecol, erow, segS, perm,
        sc1, sh1, sum2, sq2, nullptr, sc2, sh2, W3, b3, out, NT);
  }
}

// Round 3
// 935.060 us; speedup vs baseline: 20.6414x; 1.4588x over previous
//
#include <hip/hip_runtime.h>
#include <hip/hip_bf16.h>

#define NSEG 128
#define H64 64
#define C1 256   // 4H
#define K1 128   // 2H
#define C2 64    // H
#define EPSV 1e-5f
#define TPB 8    // 64-edge tiles per block

typedef __attribute__((ext_vector_type(8))) short bf16x8;
typedef __attribute__((ext_vector_type(16))) float f32x16;

__device__ __forceinline__ unsigned short f2bf(float f){
  unsigned int x = __float_as_uint(f);
  x += 0x7fffu + ((x >> 16) & 1u);   // RNE
  return (unsigned short)(x >> 16);
}
__device__ __forceinline__ float bf2f(unsigned short u){
  return __uint_as_float(((unsigned int)u) << 16);
}

// ---------------- prep ----------------
__global__ void k_cvt_emb(const float* __restrict__ src, unsigned short* __restrict__ dst, int n4){
  int i = blockIdx.x * blockDim.x + threadIdx.x;
  if (i >= n4) return;
  float4 v = ((const float4*)src)[i];
  unsigned int a = (unsigned int)f2bf(v.x) | ((unsigned int)f2bf(v.y) << 16);
  unsigned int b = (unsigned int)f2bf(v.z) | ((unsigned int)f2bf(v.w) << 16);
  ((uint2*)dst)[i] = make_uint2(a, b);
}

__global__ void k_cvt_w(const float* __restrict__ W1, const float* __restrict__ W2,
                        unsigned short* __restrict__ W1T, unsigned short* __restrict__ W2T){
  int i = blockIdx.x * blockDim.x + threadIdx.x;
  if (i < C1 * K1){                       // W1T[c][k] = W1[k][c]
    int c = i >> 7, k = i & 127;
    W1T[i] = f2bf(W1[k * C1 + c]);
  } else {
    int j = i - C1 * K1;
    if (j < C2 * C1){                     // W2T[c][k] = W2[k][c]
      int c = j >> 8, k = j & 255;
      W2T[j] = f2bf(W2[k * C2 + c]);
    }
  }
}

// ---------------- counting sort by segment ----------------
__global__ void k_hist(const int* __restrict__ col, const int* __restrict__ batch,
                       int* __restrict__ segE, int* __restrict__ cnt, int E){
  __shared__ int h[NSEG];
  for (int i = threadIdx.x; i < NSEG; i += blockDim.x) h[i] = 0;
  __syncthreads();
  int stride = gridDim.x * blockDim.x;
  for (int e = blockIdx.x * blockDim.x + threadIdx.x; e < E; e += stride){
    int s = batch[col[e]];
    segE[e] = s;
    atomicAdd(&h[s], 1);
  }
  __syncthreads();
  for (int i = threadIdx.x; i < NSEG; i += blockDim.x)
    if (h[i]) atomicAdd(&cnt[i], h[i]);
}

__global__ void k_scan(const int* __restrict__ cnt, int* __restrict__ cursor,
                       float* __restrict__ cntf){
  if (threadIdx.x == 0){
    int acc = 0;
    for (int i = 0; i < NSEG; i++){ cursor[i] = acc; acc += cnt[i]; }
  }
  if (threadIdx.x < NSEG){
    int c = cnt[threadIdx.x];
    cntf[threadIdx.x] = (float)(c > 0 ? c : 1);
  }
}

__global__ void k_scatter(const int* __restrict__ segE, const int* __restrict__ ei,
                          int* __restrict__ cursor, int* __restrict__ perm,
                          int* __restrict__ segS, int* __restrict__ ecol, int* __restrict__ erow,
                          int E, int epb){
  __shared__ int h[NSEG];
  __shared__ int base[NSEG];
  int b0 = blockIdx.x * epb;
  int b1 = b0 + epb < E ? b0 + epb : E;
  for (int i = threadIdx.x; i < NSEG; i += blockDim.x) h[i] = 0;
  __syncthreads();
  for (int e = b0 + threadIdx.x; e < b1; e += blockDim.x) atomicAdd(&h[segE[e]], 1);
  __syncthreads();
  for (int i = threadIdx.x; i < NSEG; i += blockDim.x)
    base[i] = h[i] ? atomicAdd(&cursor[i], h[i]) : 0;
  __syncthreads();
  for (int i = threadIdx.x; i < NSEG; i += blockDim.x) h[i] = 0;
  __syncthreads();
  for (int e = b0 + threadIdx.x; e < b1; e += blockDim.x){
    int s = segE[e];
    int p = base[s] + atomicAdd(&h[s], 1);
    perm[p] = e; segS[p] = s;
    ecol[p] = ei[e]; erow[p] = ei[(size_t)E + e];
  }
}

// ---------------- async staging: 64-edge f12 tile -> LDS (swizzled semantic layout) ----------------
// semantic layout: f12[edge 64][ch 128] bf16, row 256B = 16x 16B-units; unit stored at (u ^ (e&15)).
__device__ __forceinline__ void stage(char* dstbase, const int* scol, const int* srow,
                                      const unsigned short* ebf, int w, int lane){
  #pragma unroll
  for (int i = 0; i < 4; i++){
    int p = w * 256 + i * 64 + lane;          // linear 16B-unit index
    int e = p >> 4, q = p & 15;
    int u = q ^ (e & 15);                      // semantic unit landing at linear q
    const unsigned short* g = (u < 8) ? (ebf + (size_t)scol[e] * H64 + u * 8)
                                      : (ebf + (size_t)srow[e] * H64 + (u - 8) * 8);
    __builtin_amdgcn_global_load_lds((const __attribute__((address_space(1))) void*)g,
                                     (__attribute__((address_space(3))) void*)(dstbase + (w * 256 + i * 64) * 16),
                                     16, 0, 0);
  }
}

// f12 read helper: semantic unit (2kk+g) of row e
__device__ __forceinline__ bf16x8 ld_f12(const char* f12, int e, int unit){
  return *(const bf16x8*)(f12 + e * 256 + ((unit ^ (e & 15)) << 4));
}

// ---------------- pass 1: GEMM1 (unswapped) + per-(seg,ch) stats ----------------
__global__ void __launch_bounds__(256)
k_stats1(const unsigned short* __restrict__ ebf, const unsigned short* __restrict__ W1T,
         const int* __restrict__ ecol, const int* __restrict__ erow, const int* __restrict__ segS,
         float* __restrict__ sum1, float* __restrict__ sq1, int NT)
{
  __shared__ __align__(16) char f12b[2][16384];
  __shared__ int s_col[3][64], s_row[3][64], s_seg[3][64];
  const int tid = threadIdx.x, lane = tid & 63, w = tid >> 6;
  const int g = lane >> 5, l31 = lane & 31;
  float psum[2] = {0.f, 0.f}, psq[2] = {0.f, 0.f};
  int cur = -1;

  auto flush = [&](int seg){
    if (seg >= 0){
      #pragma unroll
      for (int nt = 0; nt < 2; nt++){
        float sv = psum[nt]; sv += __shfl_xor(sv, 32);
        float qv = psq[nt];  qv += __shfl_xor(qv, 32);
        if (lane < 32){
          atomicAdd(&sum1[seg * C1 + w * 64 + nt * 32 + l31], sv);
          atomicAdd(&sq1 [seg * C1 + w * 64 + nt * 32 + l31], qv);
        }
        psum[nt] = 0.f; psq[nt] = 0.f;
      }
    }
  };

  const int t0 = blockIdx.x * TPB;
  const int nT = (NT - t0 < TPB) ? (NT - t0) : TPB;

  if (tid < 64){
    int p = t0 * 64 + tid;
    s_col[0][tid] = ecol[p]; s_row[0][tid] = erow[p]; s_seg[0][tid] = segS[p];
  }
  __syncthreads();
  stage(f12b[0], s_col[0], s_row[0], ebf, w, lane);
  if (tid < 64 && nT > 1){
    int p = (t0 + 1) * 64 + tid;
    s_col[1][tid] = ecol[p]; s_row[1][tid] = erow[p]; s_seg[1][tid] = segS[p];
  }
  asm volatile("s_waitcnt vmcnt(0)" ::: "memory");
  __syncthreads();

  for (int li = 0; li < nT; ++li){
    if (li + 1 < nT)
      stage(f12b[(li + 1) & 1], s_col[(li + 1) % 3], s_row[(li + 1) % 3], ebf, w, lane);
    if (tid < 64 && li + 2 < nT){
      int p = (t0 + li + 2) * 64 + tid;
      int b = (li + 2) % 3;
      s_col[b][tid] = ecol[p]; s_row[b][tid] = erow[p]; s_seg[b][tid] = segS[p];
    }
    const char* f12 = f12b[li & 1];

    f32x16 acc[2][2];
    #pragma unroll
    for (int mt = 0; mt < 2; mt++)
      #pragma unroll
      for (int nt = 0; nt < 2; nt++)
        #pragma unroll
        for (int r = 0; r < 16; r++) acc[mt][nt][r] = 0.f;

    #pragma unroll
    for (int kk = 0; kk < 8; kk++){
      bf16x8 afr[2], bfr[2];
      #pragma unroll
      for (int mt = 0; mt < 2; mt++) afr[mt] = ld_f12(f12, mt * 32 + l31, 2 * kk + g);
      #pragma unroll
      for (int nt = 0; nt < 2; nt++)
        bfr[nt] = *(const bf16x8*)(W1T + (size_t)(w * 64 + nt * 32 + l31) * K1 + kk * 16 + g * 8);
      #pragma unroll
      for (int mt = 0; mt < 2; mt++)
        #pragma unroll
        for (int nt = 0; nt < 2; nt++)
          acc[mt][nt] = __builtin_amdgcn_mfma_f32_32x32x16_bf16(afr[mt], bfr[nt], acc[mt][nt], 0, 0, 0);
    }

    const int* seg = s_seg[li % 3];
    int sA = seg[0], sB = seg[63];
    if (sA == sB){
      if (sA != cur){ flush(cur); cur = sA; }
      #pragma unroll
      for (int mt = 0; mt < 2; mt++)
        #pragma unroll
        for (int nt = 0; nt < 2; nt++)
          #pragma unroll
          for (int r = 0; r < 16; r++){
            float v = acc[mt][nt][r];
            psum[nt] += v; psq[nt] += v * v;
          }
    } else {
      flush(cur); cur = -1;
      for (int s = sA; s <= sB; s++){
        float ts[2] = {0.f, 0.f}, tq[2] = {0.f, 0.f};
        #pragma unroll
        for (int mt = 0; mt < 2; mt++)
          #pragma unroll
          for (int r = 0; r < 16; r++){
            int e = mt * 32 + (r & 3) + 8 * (r >> 2) + 4 * g;
            bool m = (seg[e] == s);
            #pragma unroll
            for (int nt = 0; nt < 2; nt++){
              float v = m ? acc[mt][nt][r] : 0.f;
              ts[nt] += v; tq[nt] += v * v;
            }
          }
        #pragma unroll
        for (int nt = 0; nt < 2; nt++){
          float sv = ts[nt]; sv += __shfl_xor(sv, 32);
          float qv = tq[nt]; qv += __shfl_xor(qv, 32);
          if (lane < 32){
            atomicAdd(&sum1[s * C1 + w * 64 + nt * 32 + l31], sv);
            atomicAdd(&sq1 [s * C1 + w * 64 + nt * 32 + l31], qv);
          }
        }
      }
    }
    asm volatile("s_waitcnt vmcnt(0)" ::: "memory");
    __syncthreads();
  }
  flush(cur);
}

// ---------------- finalize stats -> scale/shift ----------------
__global__ void k_fin(const float* __restrict__ sum, const float* __restrict__ sq,
                      const float* __restrict__ cntf,
                      float* __restrict__ sc, float* __restrict__ sh, int C){
  int i = blockIdx.x * blockDim.x + threadIdx.x;
  if (i >= NSEG * C) return;
  int s = i / C;
  float c = cntf[s];
  float m = sum[i] / c;
  float v = fmaxf(sq[i] / c - m * m, 0.f);
  float inv = rsqrtf(v + EPSV);
  sc[i] = inv;
  sh[i] = -m * inv;
}

// ---------------- pass 2: GEMM1(swapped)+norm1+GEMM2 ----------------
// MODE 0: stats2 + store y2 ; MODE 1: stats2 only ; MODE 2: final output
template<int MODE>
__global__ void __launch_bounds__(256)
k_mid(const unsigned short* __restrict__ ebf, const unsigned short* __restrict__ W1T,
      const unsigned short* __restrict__ W2T,
      const int* __restrict__ ecol, const int* __restrict__ erow,
      const int* __restrict__ segS, const int* __restrict__ perm,
      const float* __restrict__ sc1, const float* __restrict__ sh1,
      float* __restrict__ sum2, float* __restrict__ sq2,
      unsigned short* __restrict__ y2,
      const float* __restrict__ sc2, const float* __restrict__ sh2,
      const float* __restrict__ W3, const float* __restrict__ b3,
      float* __restrict__ out, int NT)
{
  __shared__ __align__(16) char f12b[2][16384];
  __shared__ __align__(16) char h1b[32768];    // h1[edge 64][ch 256] bf16, row 512B = 32 units, unit^= (e&31)
  __shared__ int s_col[3][64], s_row[3][64], s_seg[3][64];
  __shared__ float redL[4][64];
  const int tid = threadIdx.x, lane = tid & 63, w = tid >> 6;
  const int g = lane >> 5, l31 = lane & 31;
  const int eh = w & 1;                       // gemm2 edge-half
  const int c2 = (w >> 1) * 32 + l31;         // gemm2 output channel
  float psum = 0.f, psq = 0.f; int cur = -1;
  float w3v = 0.f, b3v = 0.f;
  if (MODE == 2){ w3v = W3[c2]; b3v = b3[0]; }

  auto flush2 = [&](int seg){
    if (seg >= 0){
      float sv = psum; sv += __shfl_xor(sv, 32);
      float qv = psq;  qv += __shfl_xor(qv, 32);
      if (lane < 32){
        atomicAdd(&sum2[seg * C2 + c2], sv);
        atomicAdd(&sq2 [seg * C2 + c2], qv);
      }
      psum = 0.f; psq = 0.f;
    }
  };

  const int t0 = blockIdx.x * TPB;
  const int nT = (NT - t0 < TPB) ? (NT - t0) : TPB;

  if (tid < 64){
    int p = t0 * 64 + tid;
    s_col[0][tid] = ecol[p]; s_row[0][tid] = erow[p]; s_seg[0][tid] = segS[p];
  }
  __syncthreads();
  stage(f12b[0], s_col[0], s_row[0], ebf, w, lane);
  if (tid < 64 && nT > 1){
    int p = (t0 + 1) * 64 + tid;
    s_col[1][tid] = ecol[p]; s_row[1][tid] = erow[p]; s_seg[1][tid] = segS[p];
  }
  asm volatile("s_waitcnt vmcnt(0)" ::: "memory");
  __syncthreads();

  for (int li = 0; li < nT; ++li){
    if (tid < 64 && li + 2 < nT){
      int p = (t0 + li + 2) * 64 + tid;
      int b = (li + 2) % 3;
      s_col[b][tid] = ecol[p]; s_row[b][tid] = erow[p]; s_seg[b][tid] = segS[p];
    }
    const char* f12 = f12b[li & 1];
    const int* seg = s_seg[li % 3];

    // ---- GEMM1 swapped: C[ch][edge], mfma(A=W1T frag, B=f12 frag) ----
    f32x16 acc1[2][2];   // [mt: ch 32-tiles][nt: edge 32-tiles]
    #pragma unroll
    for (int mt = 0; mt < 2; mt++)
      #pragma unroll
      for (int nt = 0; nt < 2; nt++)
        #pragma unroll
        for (int r = 0; r < 16; r++) acc1[mt][nt][r] = 0.f;

    #pragma unroll
    for (int kk = 0; kk < 8; kk++){
      bf16x8 afr[2], bfr[2];
      #pragma unroll
      for (int mt = 0; mt < 2; mt++)
        afr[mt] = *(const bf16x8*)(W1T + (size_t)(w * 64 + mt * 32 + l31) * K1 + kk * 16 + g * 8);
      #pragma unroll
      for (int nt = 0; nt < 2; nt++) bfr[nt] = ld_f12(f12, nt * 32 + l31, 2 * kk + g);
      #pragma unroll
      for (int mt = 0; mt < 2; mt++)
        #pragma unroll
        for (int nt = 0; nt < 2; nt++)
          acc1[mt][nt] = __builtin_amdgcn_mfma_f32_32x32x16_bf16(afr[mt], bfr[nt], acc1[mt][nt], 0, 0, 0);
    }

    // ---- norm1 + relu -> h1 (packed b64 swizzled writes); seg-agnostic (per-lane seg) ----
    #pragma unroll
    for (int nt = 0; nt < 2; nt++){
      int edge = nt * 32 + l31;
      int sg = seg[edge];
      #pragma unroll
      for (int mt = 0; mt < 2; mt++)
        #pragma unroll
        for (int rq = 0; rq < 4; rq++){
          int chq = w * 64 + mt * 32 + rq * 8 + g * 4;
          float4 sc = *(const float4*)(sc1 + sg * C1 + chq);
          float4 sh = *(const float4*)(sh1 + sg * C1 + chq);
          float h0 = fmaxf(fmaf(acc1[mt][nt][rq * 4 + 0], sc.x, sh.x), 0.f);
          float h1v = fmaxf(fmaf(acc1[mt][nt][rq * 4 + 1], sc.y, sh.y), 0.f);
          float h2 = fmaxf(fmaf(acc1[mt][nt][rq * 4 + 2], sc.z, sh.z), 0.f);
          float h3 = fmaxf(fmaf(acc1[mt][nt][rq * 4 + 3], sc.w, sh.w), 0.f);
          uint2 pk;
          pk.x = (unsigned int)f2bf(h0) | ((unsigned int)f2bf(h1v) << 16);
          pk.y = (unsigned int)f2bf(h2) | ((unsigned int)f2bf(h3) << 16);
          int unit = 8 * w + 4 * mt + rq;                    // (chq*2)>>4
          int byte = edge * 512 + (((unit ^ (edge & 31)) & 31) << 4) + g * 8;
          *(uint2*)(h1b + byte) = pk;
        }
    }
    __syncthreads();                                          // h1 ready; f12[cur] consumed

    // prefetch next tile (drained at end-of-tile barrier; overlaps gemm2)
    if (li + 1 < nT)
      stage(f12b[(li + 1) & 1], s_col[(li + 1) % 3], s_row[(li + 1) % 3], ebf, w, lane);

    // ---- GEMM2 unswapped: C[edge][c2], mfma(A=h1 frag, B=W2T frag) ----
    f32x16 acc2;
    #pragma unroll
    for (int r = 0; r < 16; r++) acc2[r] = 0.f;
    #pragma unroll
    for (int kk = 0; kk < 16; kk++){
      int edge = eh * 32 + l31;
      int unit = 2 * kk + g;
      bf16x8 a = *(const bf16x8*)(h1b + edge * 512 + (((unit ^ (edge & 31)) & 31) << 4));
      bf16x8 b = *(const bf16x8*)(W2T + (size_t)c2 * C1 + kk * 16 + g * 8);
      acc2 = __builtin_amdgcn_mfma_f32_32x32x16_bf16(a, b, acc2, 0, 0, 0);
    }

    const int p0 = (t0 + li) * 64;
    int sA = seg[0], sB = seg[63];
    if (MODE < 2){
      if (sA == sB){
        if (sA != cur){ flush2(cur); cur = sA; }
        #pragma unroll
        for (int r = 0; r < 16; r++){ float v = acc2[r]; psum += v; psq += v * v; }
      } else {
        flush2(cur); cur = -1;
        for (int s = sA; s <= sB; s++){
          float ts = 0.f, tq = 0.f;
          #pragma unroll
          for (int r = 0; r < 16; r++){
            int e = eh * 32 + (r & 3) + 8 * (r >> 2) + 4 * g;
            float v = (seg[e] == s) ? acc2[r] : 0.f;
            ts += v; tq += v * v;
          }
          float sv = ts; sv += __shfl_xor(sv, 32);
          float qv = tq; qv += __shfl_xor(qv, 32);
          if (lane < 32){
            atomicAdd(&sum2[s * C2 + c2], sv);
            atomicAdd(&sq2 [s * C2 + c2], qv);
          }
        }
      }
      if (MODE == 0){
        #pragma unroll
        for (int r = 0; r < 16; r++){
          int e = eh * 32 + (r & 3) + 8 * (r >> 2) + 4 * g;
          y2[(size_t)(p0 + e) * C2 + c2] = f2bf(acc2[r]);
        }
      }
    } else {
      // MODE 2: norm2 + relu + W3 dot
      __syncthreads();                       // protect redL from previous tile's readers
      bool uni = (sA == sB);
      float scu = 0.f, shu = 0.f;
      if (uni){ scu = sc2[sA * C2 + c2]; shu = sh2[sA * C2 + c2]; }
      #pragma unroll
      for (int r = 0; r < 16; r++){
        int e = eh * 32 + (r & 3) + 8 * (r >> 2) + 4 * g;
        float scv = scu, shv = shu;
        if (!uni){
          int s = seg[e];
          scv = sc2[s * C2 + c2]; shv = sh2[s * C2 + c2];
        }
        float v = fmaxf(fmaf(acc2[r], scv, shv), 0.f) * w3v;
        v += __shfl_xor(v, 1); v += __shfl_xor(v, 2);
        v += __shfl_xor(v, 4); v += __shfl_xor(v, 8); v += __shfl_xor(v, 16);
        if (l31 == 0) redL[w][e] = v;
      }
      __syncthreads();
      if (tid < 64){
        int ehh = tid >> 5;
        float o = redL[ehh][tid] + redL[ehh + 2][tid] + b3v;
        out[perm[p0 + tid]] = o;
      }
    }

    asm volatile("s_waitcnt vmcnt(0)" ::: "memory");
    __syncthreads();
  }
  if (MODE < 2) flush2(cur);
}

// ---------------- pass 3: norm2 + relu + W3 dot (from stored y2) ----------------
__global__ void k_out(const unsigned short* __restrict__ y2, const int* __restrict__ segS,
                      const int* __restrict__ perm, const float* __restrict__ sc2,
                      const float* __restrict__ sh2, const float* __restrict__ W3,
                      const float* __restrict__ b3, float* __restrict__ out, int E)
{
  const int lane = threadIdx.x & 63;
  const int wid = (blockIdx.x * blockDim.x + threadIdx.x) >> 6;
  const int nw = (gridDim.x * blockDim.x) >> 6;
  const int es = lane >> 3;        // edge sub-index within wave (0..7)
  const int cp = (lane & 7) * 8;   // channel base (8 per lane)
  float w3r[8];
  #pragma unroll
  for (int j = 0; j < 8; j++) w3r[j] = W3[cp + j];
  const float b3v = b3[0];
  for (long base = (long)wid * 8; base < E; base += (long)nw * 8){
    int pos = (int)base + es;
    float a = 0.f;
    if (pos < E){
      bf16x8 v = *(const bf16x8*)(y2 + (size_t)pos * C2 + cp);
      int s = segS[pos];
      const float* scp = sc2 + s * C2 + cp;
      const float* shp = sh2 + s * C2 + cp;
      #pragma unroll
      for (int j = 0; j < 8; j++){
        float hv = fmaxf(fmaf(bf2f((unsigned short)v[j]), scp[j], shp[j]), 0.f);
        a = fmaf(hv, w3r[j], a);
      }
    }
    a += __shfl_xor(a, 1); a += __shfl_xor(a, 2); a += __shfl_xor(a, 4);
    if ((lane & 7) == 0 && pos < E) out[perm[pos]] = a + b3v;
  }
}

// ---------------- launch ----------------
extern "C" void kernel_launch(void* const* d_in, const int* in_sizes, int n_in,
                              void* d_out, int out_size, void* d_ws, size_t ws_size,
                              hipStream_t stream)
{
  const float* emb   = (const float*)d_in[0];
  const int*   ei    = (const int*)d_in[1];
  const int*   batch = (const int*)d_in[2];
  const float* W1    = (const float*)d_in[3];
  const float* W2    = (const float*)d_in[5];
  const float* W3    = (const float*)d_in[7];
  const float* b3    = (const float*)d_in[8];
  float* out = (float*)d_out;
  const int E = in_sizes[1] / 2;
  const int N = in_sizes[0] / H64;
  const int NT = E / 64;

  char* ws = (char*)d_ws;
  size_t o = 0;
  auto al = [&](size_t b){ size_t r = o; o = (o + b + 255) & ~((size_t)255); return r; };
  size_t o_ebf  = al((size_t)N * H64 * 2);
  size_t o_w1t  = al((size_t)C1 * K1 * 2);
  size_t o_w2t  = al((size_t)C2 * C1 * 2);
  size_t o_perm = al((size_t)E * 4);
  size_t o_segS = al((size_t)E * 4);
  size_t o_ecol = al((size_t)E * 4);
  size_t o_erow = al((size_t)E * 4);
  size_t o_cnt  = al(NSEG * 4);
  size_t o_cur  = al(NSEG * 4);
  size_t o_cntf = al(NSEG * 4);
  size_t o_sum1 = al((size_t)NSEG * C1 * 4);
  size_t o_sq1  = al((size_t)NSEG * C1 * 4);
  size_t o_sum2 = al((size_t)NSEG * C2 * 4);
  size_t o_sq2  = al((size_t)NSEG * C2 * 4);
  size_t o_sc1  = al((size_t)NSEG * C1 * 4);
  size_t o_sh1  = al((size_t)NSEG * C1 * 4);
  size_t o_sc2  = al((size_t)NSEG * C2 * 4);
  size_t o_sh2  = al((size_t)NSEG * C2 * 4);
  size_t o_segE = al((size_t)E * 4);
  size_t o_y2   = o_segE;                 // y2 aliases segE (segE dead after sort)
  size_t need_full = o_segE + (size_t)E * C2 * 2;
  const bool full = ws_size >= need_full;

  unsigned short* ebf = (unsigned short*)(ws + o_ebf);
  unsigned short* W1T = (unsigned short*)(ws + o_w1t);
  unsigned short* W2T = (unsigned short*)(ws + o_w2t);
  int* perm = (int*)(ws + o_perm);
  int* segS = (int*)(ws + o_segS);
  int* ecol = (int*)(ws + o_ecol);
  int* erow = (int*)(ws + o_erow);
  int* cnt  = (int*)(ws + o_cnt);
  int* curp = (int*)(ws + o_cur);
  float* cntf = (float*)(ws + o_cntf);
  float* sum1 = (float*)(ws + o_sum1);
  float* sq1  = (float*)(ws + o_sq1);
  float* sum2 = (float*)(ws + o_sum2);
  float* sq2  = (float*)(ws + o_sq2);
  float* sc1  = (float*)(ws + o_sc1);
  float* sh1  = (float*)(ws + o_sh1);
  float* sc2  = (float*)(ws + o_sc2);
  float* sh2  = (float*)(ws + o_sh2);
  int* segE = (int*)(ws + o_segE);
  unsigned short* y2 = (unsigned short*)(ws + o_y2);

  hipMemsetAsync(ws + o_cnt, 0, o_sc1 - o_cnt, stream);

  k_cvt_emb<<<(N * H64 / 4 + 255) / 256, 256, 0, stream>>>(emb, ebf, N * H64 / 4);
  k_cvt_w<<<192, 256, 0, stream>>>(W1, W2, W1T, W2T);

  k_hist<<<2048, 256, 0, stream>>>(ei, batch, segE, cnt, E);
  k_scan<<<1, 128, 0, stream>>>(cnt, curp, cntf);
  const int epb = 2048;
  k_scatter<<<(E + epb - 1) / epb, 256, 0, stream>>>(segE, ei, curp, perm, segS, ecol, erow, E, epb);

  const int nB = (NT + TPB - 1) / TPB;
  k_stats1<<<nB, 256, 0, stream>>>(ebf, W1T, ecol, erow, segS, sum1, sq1, NT);
  k_fin<<<(NSEG * C1) / 256, 256, 0, stream>>>(sum1, sq1, cntf, sc1, sh1, C1);

  if (full){
    k_mid<0><<<nB, 256, 0, stream>>>(ebf, W1T, W2T, ecol, erow, segS, perm,
        sc1, sh1, sum2, sq2, y2, sc2, sh2, W3, b3, out, NT);
    k_fin<<<(NSEG * C2) / 256, 256, 0, stream>>>(sum2, sq2, cntf, sc2, sh2, C2);
    k_out<<<1024, 256, 0, stream>>>(y2, segS, perm, sc2, sh2, W3, b3, out, E);
  } else {
    k_mid<1><<<nB, 256, 0, stream>>>(ebf, W1T, W2T, ecol, erow, segS, perm,
        sc1, sh1, sum2, sq2, nullptr, sc2, sh2, W3, b3, out, NT);
    k_fin<<<(NSEG * C2) / 256, 256, 0, stream>>>(sum2, sq2, cntf, sc2, sh2, C2);
    k_mid<2><<<nB, 256, 0, stream>>>(ebf, W1T, W2T, ecol, erow, segS, perm,
        sc1, sh1, sum2, sq2, nullptr, sc2, sh2, W3, b3, out, NT);
  }
}